// Round 3
// baseline (437.367 us; speedup 1.0000x reference)
//
#include <hip/hip_runtime.h>
#include <hip/hip_bf16.h>
#include <stdint.h>

// Int8Linear: per-row symmetric int8 quant (w per-output-channel, x per-token),
// int8 GEMM (exact int32 accum via MFMA i8), fused dequant + bf16 bias epilogue.
// M=8192, K=4096, N=4096 for this problem instance.
//
// R6 changes vs R5 (sync structure ONLY; staging math/swizzle/quant identical):
//  - K-tile body split into 4 phases (one 32-row M-subtile q each):
//    {ds_read frags; [stage issue ph0/ph1]; s_barrier; lgkmcnt(0);
//     sched_barrier; setprio(1); 8 MFMA; setprio(0); sched_barrier; s_barrier}
//    This is the m201/T3+T4+T5 8-phase schedule adapted to i8 (4 phases/tile,
//    2 tiles worth = 8 phase-units). R5 was the "2-phase" lockstep structure
//    whose stage+drain+barrier serialization capped MfmaUtil at 36%.
//  - All 8 prefetch gload_lds issued in phases 0-1 (>=3 phases of lead time);
//    one vmcnt(0) at tile end (loads already landed -> near-zero stall).

using i32x4  = __attribute__((ext_vector_type(4))) int;
using i32x16 = __attribute__((ext_vector_type(16))) int;

#define BM 256
#define BN 256
#define BKB 128   // K-bytes (= int8 k-elems) per LDS tile

// ---------------------------------------------------------------------------
// Fused per-row quantization for both W [N,K] and X [M,K]; one WAVE per row.
// ---------------------------------------------------------------------------
__global__ __launch_bounds__(256) void quant_rows_wave(
    const float* __restrict__ w_in, const float* __restrict__ x_in,
    int8_t* __restrict__ w_q, int8_t* __restrict__ x_q,
    float* __restrict__ w_s, float* __restrict__ x_s,
    int nw, int nrows, int K)
{
    const int wave_id = (int)((blockIdx.x * (unsigned)blockDim.x + threadIdx.x) >> 6);
    if (wave_id >= nrows) return;
    const int lane = threadIdx.x & 63;

    const bool is_w = (wave_id < nw);
    const int row = is_w ? wave_id : (wave_id - nw);
    const float* r = (is_w ? w_in : x_in) + (size_t)row * K;
    int8_t* qout   = (is_w ? w_q : x_q) + (size_t)row * K;
    float* scales  = is_w ? w_s : x_s;

    float4 v[16];
#pragma unroll
    for (int i = 0; i < 16; ++i)
        v[i] = *(const float4*)(r + i * 256 + lane * 4);

    float amax = 0.f;
#pragma unroll
    for (int i = 0; i < 16; ++i) {
        amax = fmaxf(amax, fmaxf(fmaxf(fabsf(v[i].x), fabsf(v[i].y)),
                                 fmaxf(fabsf(v[i].z), fabsf(v[i].w))));
    }

#pragma unroll
    for (int off = 32; off >= 1; off >>= 1)
        amax = fmaxf(amax, __shfl_xor(amax, off));

    const float scale = fmaxf(amax / 127.0f, 1e-12f);
    if (lane == 0) scales[row] = scale;
    const float inv = 1.0f / scale;

#pragma unroll
    for (int i = 0; i < 16; ++i) {
        float q0 = fminf(fmaxf(rintf(v[i].x * inv), -128.f), 127.f);
        float q1 = fminf(fmaxf(rintf(v[i].y * inv), -128.f), 127.f);
        float q2 = fminf(fmaxf(rintf(v[i].z * inv), -128.f), 127.f);
        float q3 = fminf(fmaxf(rintf(v[i].w * inv), -128.f), 127.f);
        union { signed char c[4]; int i32; } u;
        u.c[0] = (signed char)(int)q0;
        u.c[1] = (signed char)(int)q1;
        u.c[2] = (signed char)(int)q2;
        u.c[3] = (signed char)(int)q3;
        *(int*)(qout + i * 256 + lane * 4) = u.i32;
    }
}

// ---------------------------------------------------------------------------
// int8 GEMM: C[M][N] = A[M][K] . B[N][K]^T, int32 accum, fused dequant.
// 256x256 tile, BK=128 i8 (128B rows), 8 waves (2M x 4N, 128x64 each),
// 32x32x32 i8 MFMA, double-buffered LDS, 4-phase schedule per K-tile.
//
// LDS layout: row-major [256 rows][128 B], 16B chunks swizzled:
//   phys_chunk = log_chunk ^ (row & 7)
// Staged via global_load_lds (linear dest) with the INVERSE permutation on
// the per-thread global source chunk (R5, verified).
//
// Frag reads: lane reads 16B at row = base + (lane&31),
//   log_chunk = ks*2 + (lane>>5), phys = log_chunk ^ (row&7).
// C/D: col = lane&31, row = (reg&3) + 8*(reg>>2) + 4*(lane>>5)  [m74/m101]
//
// Sync per K-tile (4 phases, q = M-subtile):
//   ph q: ds_read A-frags(q) [+ B-frags all, ph0]
//         [ph0: stage A(t+1); ph1: stage B(t+1)]  -> buf^1 (never read in t)
//         s_barrier; lgkmcnt(0); sched_barrier;
//         setprio(1); 8 MFMA; setprio(0); sched_barrier;
//         [ph3: vmcnt(0)]  s_barrier
// Hazard audit: buf^1 reads all completed before tile t-1's closing barrier
// (per-phase lgkmcnt(0)), so stages issued anywhere in tile t are safe.
// ---------------------------------------------------------------------------
__global__ __launch_bounds__(512, 2) void gemm_i8_256(
    const int8_t* __restrict__ A,   // [M][K] x_i8
    const int8_t* __restrict__ B,   // [N][K] w_i8
    const float*  __restrict__ xs,  // [M]
    const float*  __restrict__ ws,  // [N]
    const float*  __restrict__ bias,// [N]
    float*        __restrict__ out, // [M][N] fp32
    int M, int N, int K)
{
    __shared__ int8_t sA[2][BM * BKB];   // 2 x 32 KiB
    __shared__ int8_t sB[2][BN * BKB];   // 2 x 32 KiB

    const int tid   = threadIdx.x;
    const int wave  = tid >> 6;
    const int lane  = tid & 63;
    const int l31   = lane & 31;
    const int lhalf = lane >> 5;        // 0/1
    const int rot   = l31 & 7;          // read-side swizzle rotation

    const int bm = blockIdx.y * BM;
    const int bn = blockIdx.x * BN;
    const int wm = (wave >> 2) * 128;   // 2 M-waves
    const int wn = (wave & 3) * 64;     // 4 N-waves

    i32x16 acc[4][2];
#pragma unroll
    for (int q = 0; q < 4; ++q)
#pragma unroll
        for (int n = 0; n < 2; ++n)
#pragma unroll
            for (int r = 0; r < 16; ++r) acc[q][n][r] = 0;

    // staging source (inverse-swizzled chunk per thread), R5-identical
    const int srow = tid >> 3;
    const int soff = (((tid & 7) ^ ((tid >> 3) & 7)) << 4);
    const int8_t* aS = A + (size_t)(bm + srow) * K + soff;
    const int8_t* bS = B + (size_t)(bn + srow) * K + soff;
    const size_t rstep = (size_t)64 * K;

    const int NT = K / BKB;

#define STAGE4(SRC, DST)                                                     \
    {                                                                        \
        _Pragma("unroll")                                                    \
        for (int l = 0; l < 4; ++l)                                          \
            __builtin_amdgcn_global_load_lds(                                \
                (const __attribute__((address_space(1))) void*)((SRC) + l * rstep), \
                (__attribute__((address_space(3))) void*)((DST) + l * 8192 + tid * 16), \
                16, 0, 0);                                                   \
    }

    // prologue: stage tile 0 into buffer 0
    STAGE4(aS, &sA[0][0]);
    STAGE4(bS, &sB[0][0]);
    asm volatile("s_waitcnt vmcnt(0)" ::: "memory");
    __builtin_amdgcn_s_barrier();
    asm volatile("" ::: "memory");

    for (int t = 0; t < NT; ++t) {
        const int cur = t & 1;
        const int8_t* cA = &sA[cur][0];
        const int8_t* cB = &sB[cur][0];
        int8_t* nA = &sA[cur ^ 1][0];
        int8_t* nB = &sB[cur ^ 1][0];
        const size_t knext = (size_t)(t + 1) * BKB;
        const bool pf = (t + 1 < NT);   // uniform

        i32x4 bf[2][4];                 // B-frags, register-cached all tile

#pragma unroll
        for (int p = 0; p < 4; ++p) {
            // ---- ds-read section of phase p ----
            i32x4 af[4];
            {
                const int arow = wm + p * 32 + l31;
#pragma unroll
                for (int ks = 0; ks < 4; ++ks)
                    af[ks] = *(const i32x4*)(cA + arow * BKB +
                                             ((((ks << 1) | lhalf) ^ rot) << 4));
            }
            if (p == 0) {
#pragma unroll
                for (int n = 0; n < 2; ++n)
#pragma unroll
                    for (int ks = 0; ks < 4; ++ks) {
                        const int brow = wn + n * 32 + l31;
                        bf[n][ks] = *(const i32x4*)(cB + brow * BKB +
                                                    ((((ks << 1) | lhalf) ^ rot) << 4));
                    }
                if (pf) STAGE4(aS + knext, nA);
            }
            if (p == 1) {
                if (pf) STAGE4(bS + knext, nB);
            }

            // ---- sync + MFMA cluster of phase p ----
            __builtin_amdgcn_s_barrier();
            asm volatile("s_waitcnt lgkmcnt(0)" ::: "memory");
            __builtin_amdgcn_sched_barrier(0);
            __builtin_amdgcn_s_setprio(1);
#pragma unroll
            for (int n = 0; n < 2; ++n)
#pragma unroll
                for (int ks = 0; ks < 4; ++ks)
                    acc[p][n] = __builtin_amdgcn_mfma_i32_32x32x32_i8(
                        af[ks], bf[n][ks], acc[p][n], 0, 0, 0);
            __builtin_amdgcn_s_setprio(0);
            __builtin_amdgcn_sched_barrier(0);
            if (p == 3)
                asm volatile("s_waitcnt vmcnt(0)" ::: "memory");
            __builtin_amdgcn_s_barrier();
        }
    }
#undef STAGE4

    // Epilogue: out = fp32( bf16( bf16(acc*xs*ws) + bf16(bias) ) )
#pragma unroll
    for (int n = 0; n < 2; ++n) {
        const int col = bn + wn + n * 32 + l31;
        const float wsv = ws[col];
        const float bsv = __bfloat162float(__float2bfloat16(bias[col]));
#pragma unroll
        for (int q = 0; q < 4; ++q) {
            const int rowbase = bm + wm + q * 32 + 4 * lhalf;
#pragma unroll
            for (int r = 0; r < 16; ++r) {
                const int row = rowbase + (r & 3) + 8 * (r >> 2);
                const float v = (float)acc[q][n][r] * xs[row] * wsv;
                const float vb = __bfloat162float(__float2bfloat16(v));
                const float res = __bfloat162float(__float2bfloat16(vb + bsv));
                out[(size_t)row * N + col] = res;
            }
        }
    }
}

// ---------------------------------------------------------------------------
extern "C" void kernel_launch(void* const* d_in, const int* in_sizes, int n_in,
                              void* d_out, int out_size, void* d_ws, size_t ws_size,
                              hipStream_t stream)
{
    const float* x    = (const float*)d_in[0];   // [B,S,K] fp32
    const float* wfp  = (const float*)d_in[1];   // [N,K] fp32
    const float* bias = (const float*)d_in[2];   // [N] fp32
    float* out = (float*)d_out;                  // [M,N] fp32

    const int N = in_sizes[2];
    const int K = in_sizes[1] / N;
    const int M = in_sizes[0] / K;

    // workspace layout: w_i8[N*K] | x_i8[M*K] | w_scales[N] | x_scales[M]
    int8_t* w_i8 = (int8_t*)d_ws;
    int8_t* x_i8 = w_i8 + (size_t)N * K;
    float* w_scales = (float*)(x_i8 + (size_t)M * K);
    float* x_scales = w_scales + N;

    const int nrows = N + M;                     // one wave per row
    const int nblocks = (nrows + 3) / 4;         // 4 waves / 256-thread block
    quant_rows_wave<<<nblocks, 256, 0, stream>>>(wfp, x, w_i8, x_i8,
                                                 w_scales, x_scales,
                                                 N, nrows, K);

    dim3 grid(N / BN, M / BM);
    gemm_i8_256<<<grid, 512, 0, stream>>>(x_i8, w_i8, x_scales, w_scales,
                                          bias, out, M, N, K);
}